// Round 7
// baseline (115.895 us; speedup 1.0000x reference)
//
#include <hip/hip_runtime.h>
#include <stdint.h>

#define D 128
#define TM 64
#define GRID 512        // 2 blocks/CU
#define NTHREADS 256

typedef float f32x4 __attribute__((ext_vector_type(4)));
typedef float f32x2 __attribute__((ext_vector_type(2)));
typedef short s16x8 __attribute__((ext_vector_type(8)));
typedef uint32_t u32x2 __attribute__((ext_vector_type(2)));
typedef uint32_t u32x4 __attribute__((ext_vector_type(4)));

__device__ __forceinline__ short f2bf(float f) {
    union { float f; uint32_t u; } v; v.f = f;
    return (short)((v.u + 0x7fffu + ((v.u >> 16) & 1u)) >> 16);   // RNE
}
__device__ __forceinline__ uint32_t cvt_pk_bf16(float lo, float hi) {
    uint32_t r;
    asm("v_cvt_pk_bf16_f32 %0, %1, %2" : "=v"(r) : "v"(lo), "v"(hi));
    return r;
}
// async global->LDS; LDS dest = wave-uniform base + lane*size
__device__ __forceinline__ void gld16(const float* g, float* l) {
    __builtin_amdgcn_global_load_lds(
        (const __attribute__((address_space(1))) void*)g,
        (__attribute__((address_space(3))) void*)l, 16, 0, 0);
}
__device__ __forceinline__ void gld4(const int* g, int* l) {
    __builtin_amdgcn_global_load_lds(
        (const __attribute__((address_space(1))) void*)g,
        (__attribute__((address_space(3))) void*)l, 4, 0, 0);
}

__global__ __launch_bounds__(NTHREADS, 2)
void gate_agg_kernel(const float* __restrict__ X,
                     const int* __restrict__ bidx,
                     const float* __restrict__ W1,
                     const float* __restrict__ b1,
                     const float* __restrict__ W2,
                     const float* __restrict__ b2,
                     float* __restrict__ out,
                     int NT)
{
    // fp32 X tiles, double-buffered, 64 KB. Linear dest; data source-swizzled:
    // LDS(row, chunk c) holds global 16B-chunk (c ^ (row&15)) of that row.
    __shared__ float xt[2][TM * D];
    __shared__ int   idxb[2][TM];      // staged batch_idx (per-wave 16-slot slices)
    __shared__ u32x2 gid[TM];          // {gate bits, seg}; per-wave slice, same-wave use

    const int tid = threadIdx.x;
    const int l = tid & 63;
    const int w = tid >> 6;
    const int l15 = l & 15;
    const int lk = l >> 4;

    // ---- init: pack W1 (bf16, B-frag layout) into xt[0] as temp, then pull
    // ALL 32 B-fragments (full W1) into this wave's VGPRs. 128 VGPRs.
    {
        short* w1t = (short*)&xt[0][0];
        for (int i = tid; i < D * D; i += NTHREADS) {
            int k = i >> 7, n = i & 127;
            w1t[((k >> 3) * D + n) * 8 + (k & 7)] = f2bf(W1[i]);
        }
    }
    __syncthreads();
    s16x8 bfr[8][4];
    {
        const short* w1t = (const short*)&xt[0][0];
        #pragma unroll
        for (int ct = 0; ct < 8; ++ct)
            #pragma unroll
            for (int kt = 0; kt < 4; ++kt)
                bfr[ct][kt] = *(const s16x8*)&w1t[((kt * 4 + lk) * D + ct * 16 + l15) * 8];
    }
    __syncthreads();   // frag reads done before xt[0] is re-staged

    float b1v[8], w2v[8];
    #pragma unroll
    for (int ct = 0; ct < 8; ++ct) {
        b1v[ct] = b1[ct * 16 + l15];
        w2v[ct] = W2[ct * 16 + l15];
    }
    const float b2s = b2[0];

    // balanced contiguous tile range
    const int q = NT / GRID, rem = NT % GRID;
    int t0, t1;
    if ((int)blockIdx.x < rem) { t0 = blockIdx.x * (q + 1); t1 = t0 + q + 1; }
    else { t0 = rem * (q + 1) + ((int)blockIdx.x - rem) * q; t1 = t0 + q; }

    // wave w owns rows 16w..16w+15 of every tile; lane owns cols 2l,2l+1 in phase 3
    float acc3[2] = {0.f, 0.f};
    int cur = -1;

    const int lrh = l >> 5;        // row-within-pair for staging
    const int lch = l & 31;        // 16B chunk within row

    // stage tile TT's 16 own rows (+16 idx) into buffer PB: 9 gld_lds per wave
#define STAGE(TT, PB) {                                                          \
        const float* xg = X + (size_t)(TT) * (TM * D) + (16 * w) * D;            \
        float* lb = &xt[PB][(16 * w) * D];                                       \
        _Pragma("unroll")                                                        \
        for (int i = 0; i < 8; ++i) {                                            \
            const int rloc = 2 * i + lrh;                                        \
            gld16(xg + rloc * D + ((lch ^ rloc) << 2), lb + 2 * i * D);          \
        }                                                                        \
        if (l < 16) gld4(bidx + (size_t)(TT) * TM + 16 * w + l,                  \
                         &idxb[PB][16 * w]);                                     \
    }

    // ---- prologue: stage t0
    if (t0 < t1) STAGE(t0, 0);

    int cb = 0;
    for (int t = t0; t < t1; ++t, cb ^= 1) {
        // anti-dep: this wave's prior ds_reads of xt[cb^1]/idxb[cb^1] must have
        // completed before gld_lds overwrites them (vmem-write vs ds-read race)
        asm volatile("s_waitcnt lgkmcnt(0)" ::: "memory");
        __builtin_amdgcn_sched_barrier(0);

        if (t + 1 < t1) {
            STAGE(t + 1, cb ^ 1);
            __builtin_amdgcn_sched_barrier(0);
            asm volatile("s_waitcnt vmcnt(9)" ::: "memory");  // tile t ready; t+1 in flight
        } else {
            asm volatile("s_waitcnt vmcnt(0)" ::: "memory");  // last tile
        }
        __builtin_amdgcn_sched_barrier(0);

        const char* rb = (const char*)&xt[cb][0];

        // ---- phase 1: h = relu(X@W1+b1); wave's 16 rows x 128 cols; B in regs
        f32x4 acc[8];
        #pragma unroll
        for (int ct = 0; ct < 8; ++ct) acc[ct] = (f32x4)0.f;
        {
            const int R = 16 * w + l15;
            const char* rrow = rb + R * 512;
            #pragma unroll
            for (int kt = 0; kt < 4; ++kt) {
                const int kc2 = (kt * 4 + lk) * 2;
                f32x4 xa = *(const f32x4*)(rrow + ((kc2 ^ l15) << 4));
                f32x4 xb = *(const f32x4*)(rrow + (((kc2 + 1) ^ l15) << 4));
                union { u32x4 u; s16x8 s; } A;
                A.u[0] = cvt_pk_bf16(xa[0], xa[1]);
                A.u[1] = cvt_pk_bf16(xa[2], xa[3]);
                A.u[2] = cvt_pk_bf16(xb[0], xb[1]);
                A.u[3] = cvt_pk_bf16(xb[2], xb[3]);
                #pragma unroll
                for (int ct = 0; ct < 8; ++ct)
                    acc[ct] = __builtin_amdgcn_mfma_f32_16x16x32_bf16(A.s, bfr[ct][kt], acc[ct], 0, 0, 0);
            }
        }

        // ---- phase 2: in-wave gate; {g,seg} to per-wave gid slice (no barrier)
        {
            float p[4] = {0.f, 0.f, 0.f, 0.f};
            #pragma unroll
            for (int ct = 0; ct < 8; ++ct) {
                #pragma unroll
                for (int r = 0; r < 4; ++r) {
                    float h = acc[ct][r] + b1v[ct];
                    h = fmaxf(h, 0.f);
                    p[r] = fmaf(h, w2v[ct], p[r]);
                }
            }
            #pragma unroll
            for (int r = 0; r < 4; ++r) {
                p[r] += __shfl_xor(p[r], 1, 64);
                p[r] += __shfl_xor(p[r], 2, 64);
                p[r] += __shfl_xor(p[r], 4, 64);
                p[r] += __shfl_xor(p[r], 8, 64);
            }
            float ps = p[0];
            ps = (l15 == 1) ? p[1] : ps;
            ps = (l15 == 2) ? p[2] : ps;
            ps = (l15 == 3) ? p[3] : ps;
            if (l15 < 4) {
                const int rr = lk * 4 + l15;
                const int seg = idxb[cb][16 * w + rr];
                float g = 1.f / (1.f + __expf(-(ps + b2s)));
                u32x2 gi; gi[0] = __float_as_uint(g); gi[1] = (uint32_t)seg;
                gid[16 * w + rr] = gi;
            }
        }

        // ---- phase 3: segmented accumulate over wave's 16 rows; lane = 2 cols
        {
            const char* rbc = rb + (16 * w) * 512;
            #pragma unroll
            for (int r = 0; r < 16; ++r) {
                u32x2 gi = gid[16 * w + r];
                const int seg = (int)gi[1];
                const float g = __uint_as_float(gi[0]);
                if (seg != cur) {
                    if (cur >= 0) {
                        atomicAdd(out + (size_t)cur * D + 2 * l,     acc3[0]);
                        atomicAdd(out + (size_t)cur * D + 2 * l + 1, acc3[1]);
                    }
                    acc3[0] = 0.f; acc3[1] = 0.f; cur = seg;
                }
                f32x2 xv = *(const f32x2*)(rbc + r * 512 +
                            (((l >> 1) ^ r) << 4) + (l & 1) * 8);
                acc3[0] = fmaf(g, xv[0], acc3[0]);
                acc3[1] = fmaf(g, xv[1], acc3[1]);
            }
        }
        // no barriers: all staging/compute/aggregation is wave-private
    }
#undef STAGE

    if (cur >= 0) {
        atomicAdd(out + (size_t)cur * D + 2 * l,     acc3[0]);
        atomicAdd(out + (size_t)cur * D + 2 * l + 1, acc3[1]);
    }
}

extern "C" void kernel_launch(void* const* d_in, const int* in_sizes, int n_in,
                              void* d_out, int out_size, void* d_ws, size_t ws_size,
                              hipStream_t stream) {
    const float* X    = (const float*)d_in[0];
    const int*   bidx = (const int*)d_in[1];
    const float* W1   = (const float*)d_in[2];
    const float* b1   = (const float*)d_in[3];
    const float* W2   = (const float*)d_in[4];
    const float* b2   = (const float*)d_in[5];
    float* out = (float*)d_out;

    const int N  = in_sizes[0] / D;      // 1,000,000
    const int NT = N / TM;               // 15,625 tiles

    hipMemsetAsync(d_out, 0, (size_t)out_size * sizeof(float), stream);
    gate_agg_kernel<<<GRID, NTHREADS, 0, stream>>>(X, bidx, W1, b1, W2, b2, out, NT);
}

// Round 9
// 110.287 us; speedup vs baseline: 1.0509x; 1.0509x over previous
//
#include <hip/hip_runtime.h>
#include <stdint.h>

#define D 128
#define TM 64
#define GRID 512        // 2 blocks/CU * 256 CU
#define NTHREADS 512    // 8 waves/block
#define PPW 9           // pp row stride (f32), gcd(9,32)=1 -> conflict-free

typedef float f32x4 __attribute__((ext_vector_type(4)));
typedef short s16x8 __attribute__((ext_vector_type(8)));
typedef uint32_t u32x2 __attribute__((ext_vector_type(2)));

__device__ __forceinline__ short f2bf(float f) {
    union { float f; uint32_t u; } v; v.f = f;
    return (short)((v.u + 0x7fffu + ((v.u >> 16) & 1u)) >> 16);   // RNE
}
__device__ __forceinline__ uint32_t cvt_pk_bf16(float lo, float hi) {
    uint32_t r;
    asm("v_cvt_pk_bf16_f32 %0, %1, %2" : "=v"(r) : "v"(lo), "v"(hi));
    return r;
}

__global__ __launch_bounds__(NTHREADS, 2)   // 2 blocks/CU -> 16 waves/CU, VGPR<=128
void gate_agg_kernel(const float* __restrict__ X,
                     const int* __restrict__ bidx,
                     const float* __restrict__ W1,
                     const float* __restrict__ b1,
                     const float* __restrict__ W2,
                     const float* __restrict__ b2,
                     float* __restrict__ out,
                     int NT)
{
    __shared__ short xt[2][TM * D];    // bf16 tiles, chunk-swizzled, 2 x 16 KB
    __shared__ float pp[64 * PPW];     // gate partials [node][wave 0..7]
    __shared__ u32x2 gid[TM];          // {gate bits, seg}; per-wave 8-row slice

    const int tid = threadIdx.x;
    const int l = tid & 63;
    const int w = tid >> 6;            // 0..7 (8 waves)
    const int l15 = l & 15;
    const int lk = l >> 4;

    // ---- W1 col-slice to regs: wave w owns h-cols 16w..16w+15 (16 VGPR)
    // A-frag (MFMA 1st operand): lane holds W1[k = kt*32+lk*8+e][16w + l15]
    s16x8 bfr[4];
    #pragma unroll
    for (int kt = 0; kt < 4; ++kt)
        #pragma unroll
        for (int e = 0; e < 8; ++e)
            bfr[kt][e] = f2bf(W1[(kt * 32 + lk * 8 + e) * D + 16 * w + l15]);

    // per-lane bias/W2 for hcol = 16w + lk*4 + r   (D-row index)
    float b1v[4], w2v[4];
    #pragma unroll
    for (int r = 0; r < 4; ++r) {
        b1v[r] = b1[16 * w + lk * 4 + r];
        w2v[r] = W2[16 * w + lk * 4 + r];
    }
    const float b2s = b2[0];

    // balanced contiguous tile range
    const int q = NT / GRID, rem = NT % GRID;
    int t0, t1;
    if ((int)blockIdx.x < rem) { t0 = blockIdx.x * (q + 1); t1 = t0 + q + 1; }
    else { t0 = rem * (q + 1) + ((int)blockIdx.x - rem) * q; t1 = t0 + q; }

    // phase-3: wave w owns rows 8w..8w+7; lane owns cols 2l, 2l+1
    float acc3[2] = {0.f, 0.f};
    int cur = -1;

    // ---- prologue: depth-2 register prefetch (4 x f32x4 per thread per tile)
    f32x4 vA[4], vB[4];
    int ridxA = 0, ridxB = 0;
    if (t0 < t1) {
        const float* xg = X + (size_t)t0 * TM * D;
        #pragma unroll
        for (int j = 0; j < 4; ++j) vA[j] = *(const f32x4*)(xg + (size_t)(j * 512 + tid) * 4);
        if (l < 8) ridxA = bidx[(size_t)t0 * TM + 8 * w + l];
    }
    if (t0 + 1 < t1) {
        const float* xg = X + (size_t)(t0 + 1) * TM * D;
        #pragma unroll
        for (int j = 0; j < 4; ++j) vB[j] = *(const f32x4*)(xg + (size_t)(j * 512 + tid) * 4);
        if (l < 8) ridxB = bidx[(size_t)(t0 + 1) * TM + 8 * w + l];
    }

#define BODY(V, RIDX, PB)                                                        \
    {                                                                            \
        /* stage V -> bf16 swizzled xt[PB]; vmcnt waits per-use (counted) */     \
        _Pragma("unroll")                                                        \
        for (int j = 0; j < 4; ++j) {                                            \
            int qc = j * 512 + tid;                                              \
            int row = qc >> 5, cq = qc & 31;                                     \
            int c2 = cq >> 1, h = cq & 1;                                        \
            u32x2 wv;                                                            \
            wv[0] = cvt_pk_bf16(V[j][0], V[j][1]);                               \
            wv[1] = cvt_pk_bf16(V[j][2], V[j][3]);                               \
            *(u32x2*)((char*)xt[PB] + row * 256 + ((c2 ^ (row & 15)) << 4) + h * 8) = wv; \
        }                                                                        \
        const int ridx_cur = RIDX;                                               \
        /* depth-2: issue t+2 into just-freed regs (in flight all iteration) */  \
        if (t + 2 < t1) {                                                        \
            const float* xg = X + (size_t)(t + 2) * TM * D;                      \
            _Pragma("unroll")                                                    \
            for (int j = 0; j < 4; ++j)                                          \
                V[j] = *(const f32x4*)(xg + (size_t)(j * 512 + tid) * 4);        \
            if (l < 8) RIDX = bidx[(size_t)(t + 2) * TM + 8 * w + l];            \
        }                                                                        \
        asm volatile("s_waitcnt lgkmcnt(0)" ::: "memory");                       \
        __builtin_amdgcn_s_barrier();                    /* B_stage */           \
        __builtin_amdgcn_sched_barrier(0);                                       \
        /* phase 1: D[hcol][node]; A = W1-slice (regs), B = X from LDS */        \
        f32x4 acc[4];                                                            \
        acc[0] = (f32x4)0.f; acc[1] = (f32x4)0.f;                                \
        acc[2] = (f32x4)0.f; acc[3] = (f32x4)0.f;                                \
        _Pragma("unroll")                                                        \
        for (int kt = 0; kt < 4; ++kt) {                                         \
            const int kc = kt * 4 + lk;                                          \
            _Pragma("unroll")                                                    \
            for (int nf = 0; nf < 4; ++nf) {                                     \
                const int R = nf * 16 + l15;                                     \
                s16x8 xb = *(const s16x8*)((const char*)xt[PB] + R * 256 + ((kc ^ l15) << 4)); \
                acc[nf] = __builtin_amdgcn_mfma_f32_16x16x32_bf16(bfr[kt], xb, acc[nf], 0, 0, 0); \
            }                                                                    \
        }                                                                        \
        /* phase 2a: partial logits over wave's 16 hcols; reduce lk (2 shfl) */  \
        _Pragma("unroll")                                                        \
        for (int nf = 0; nf < 4; ++nf) {                                         \
            float s = 0.f;                                                       \
            _Pragma("unroll")                                                    \
            for (int r = 0; r < 4; ++r) {                                        \
                float h = acc[nf][r] + b1v[r];                                   \
                h = fmaxf(h, 0.f);                                               \
                s = fmaf(h, w2v[r], s);                                          \
            }                                                                    \
            s += __shfl_xor(s, 16, 64);                                          \
            s += __shfl_xor(s, 32, 64);                                          \
            if (l < 16) pp[(nf * 16 + l) * PPW + w] = s;                         \
        }                                                                        \
        asm volatile("s_waitcnt lgkmcnt(0)" ::: "memory");                       \
        __builtin_amdgcn_s_barrier();                    /* B_pp */              \
        __builtin_amdgcn_sched_barrier(0);                                       \
        /* phase 2b: lanes<8 finish gate for own rows 8w+l (8 waves cover 64) */ \
        if (l < 8) {                                                             \
            const int node = 8 * w + l;                                          \
            float s = 0.f;                                                       \
            _Pragma("unroll")                                                    \
            for (int c = 0; c < 8; ++c) s += pp[node * PPW + c];                 \
            float g = 1.f / (1.f + __expf(-(s + b2s)));                          \
            u32x2 gi; gi[0] = __float_as_uint(g); gi[1] = (uint32_t)ridx_cur;    \
            gid[node] = gi;                                                      \
        }                                                                        \
        asm volatile("s_waitcnt lgkmcnt(0)" ::: "memory");  /* same-wave vis */  \
        __builtin_amdgcn_sched_barrier(0);                                       \
        /* phase 3: segmented accumulate over wave's 8 rows (bf16 from LDS) */   \
        _Pragma("unroll")                                                        \
        for (int r = 0; r < 8; ++r) {                                            \
            const int row = 8 * w + r;                                           \
            u32x2 gi = gid[row];                                                 \
            const int seg = (int)gi[1];                                          \
            const float g = __uint_as_float(gi[0]);                              \
            if (seg != cur) {                                                    \
                if (cur >= 0) {                                                  \
                    atomicAdd(out + (size_t)cur * D + 2 * l,     acc3[0]);       \
                    atomicAdd(out + (size_t)cur * D + 2 * l + 1, acc3[1]);       \
                }                                                                \
                acc3[0] = 0.f; acc3[1] = 0.f; cur = seg;                         \
            }                                                                    \
            uint32_t xv = *(const uint32_t*)((const char*)xt[PB] + row * 256 +   \
                           ((((l >> 2) ^ (row & 15)) << 4)) + (l & 3) * 4);      \
            acc3[0] = fmaf(g, __uint_as_float(xv << 16),         acc3[0]);       \
            acc3[1] = fmaf(g, __uint_as_float(xv & 0xffff0000u), acc3[1]);       \
        }                                                                        \
    }

    int t = t0;
    while (t < t1) {
        BODY(vA, ridxA, 0);
        ++t; if (t >= t1) break;
        BODY(vB, ridxB, 1);
        ++t;
    }
#undef BODY

    if (cur >= 0) {
        atomicAdd(out + (size_t)cur * D + 2 * l,     acc3[0]);
        atomicAdd(out + (size_t)cur * D + 2 * l + 1, acc3[1]);
    }
}

extern "C" void kernel_launch(void* const* d_in, const int* in_sizes, int n_in,
                              void* d_out, int out_size, void* d_ws, size_t ws_size,
                              hipStream_t stream) {
    const float* X    = (const float*)d_in[0];
    const int*   bidx = (const int*)d_in[1];
    const float* W1   = (const float*)d_in[2];
    const float* b1   = (const float*)d_in[3];
    const float* W2   = (const float*)d_in[4];
    const float* b2   = (const float*)d_in[5];
    float* out = (float*)d_out;

    const int N  = in_sizes[0] / D;      // 1,000,000
    const int NT = N / TM;               // 15,625 tiles

    hipMemsetAsync(d_out, 0, (size_t)out_size * sizeof(float), stream);
    gate_agg_kernel<<<GRID, NTHREADS, 0, stream>>>(X, bidx, W1, b1, W2, b2, out, NT);
}